// Round 5
// baseline (317.859 us; speedup 1.0000x reference)
//
#include <hip/hip_runtime.h>

// Problem constants (from reference setup_inputs)
#define BB 4
#define MM 16384
#define NN 32768
#define KK 16
#define ROWS (BB * NN)   // 131072
#define OUTW 131         // 3 coords + 64 + 64
#define TPW 2            // 16-row MFMA tiles per wave
#define RPWAVE (TPW * 16)                 // 32 rows per wave
#define A_BLOCKS (ROWS / (RPWAVE * 4))    // 1024 blocks, 4 waves each
#define APAD 72          // padded k-stride of the LDS A-tile, in f16 units
                         // (72*2=144 B/row -> 4-bank row advance -> 2-way max = free)

// Lessons encoded:
//  r1-r3: NO runtime-indexed per-thread arrays; named scalars / ext_vectors with
//         static indices only (scratch demotion cost 1-2 GB of HBM traffic).
//  r1/r4: XCD swizzle validated (FETCH 211->67 MB).
//  r4:    VALU-broadcast inner product is the bottleneck (52% VALUBusy, 91 us)
//         -> replace with mfma_f32_16x16x32_f16 (this round's change).

typedef _Float16 half8 __attribute__((ext_vector_type(8)));
typedef float f32x4 __attribute__((ext_vector_type(4)));

// B-fragment (32x16 of W, f16): lane holds k = kt*32 + (lane>>4)*8 + j, col = ot*16 + (lane&15)
__device__ __forceinline__ half8 load_bfrag(const float* __restrict__ W, int lane, int ot, int kt) {
    const int kb  = kt * 32 + ((lane >> 4) << 3);
    const int col = ot * 16 + (lane & 15);
    half8 b;
#pragma unroll
    for (int j = 0; j < 8; ++j) b[j] = (_Float16)W[(kb + j) * 64 + col];
    return b;
}

// gather-max over 16 neighbors of one row; indices broadcast via readlane -> SGPR base
__device__ __forceinline__ float gmax16(const float* __restrict__ cfb, int mi, int base, int lane) {
    float a0 = -3.402823466e38f, a1 = a0;
#pragma unroll
    for (int k = 0; k < KK; k += 2) {
        const int m0 = __builtin_amdgcn_readlane(mi, base + k);
        const int m1 = __builtin_amdgcn_readlane(mi, base + k + 1);
        a0 = fmaxf(a0, cfb[((size_t)m0 << 6) + lane]);
        a1 = fmaxf(a1, cfb[((size_t)m1 << 6) + lane]);
    }
    return fmaxf(a0, a1);
}

#define MFMA16(a, b, c) __builtin_amdgcn_mfma_f32_16x16x32_f16(a, b, c, 0, 0, 0)

// ---------------------------------------------------------------------------
// Kernel 1: gather + max-pool + (pooled @ W1 + b1) via MFMA -> out[..., 3:67]
//           + coords -> out[..., 0:3]; per-channel sum/sumsq -> ws[0:128]
// ---------------------------------------------------------------------------
__global__ __launch_bounds__(256) void k_pool_proj(
    const float* __restrict__ cf, const int* __restrict__ idxs,
    const float* __restrict__ scoord,
    const float* __restrict__ W1, const float* __restrict__ b1,
    float* __restrict__ out, float* __restrict__ acc)
{
    __shared__ _Float16 ah[4][16][APAD];   // per-wave 16x64 A-tile (padded), 9.2 KB
    __shared__ float lsum[64], lsq[64];
    const int lane = threadIdx.x & 63;
    const int wv   = threadIdx.x >> 6;
    if (threadIdx.x < 64) { lsum[threadIdx.x] = 0.f; lsq[threadIdx.x] = 0.f; }
    __syncthreads();

    // XCD swizzle (validated): block w -> XCD w&7; each batch owns 2 XCDs so
    // its 4.2 MB cf slice stays L2-resident.
    const int w     = blockIdx.x;
    const int xcd   = w & 7;
    const int batch = xcd >> 1;
    const int lb    = (w >> 3) + ((xcd & 1) << 7);   // [0,256) within batch
    const int rbase = batch * NN + (lb * 4 + wv) * RPWAVE;
    const float* cfb = cf + ((size_t)batch << 20);

    // W1 fragments in registers: 8 x half8 = 32 VGPRs, loaded once per wave
    const half8 b00 = load_bfrag(W1, lane, 0, 0), b01 = load_bfrag(W1, lane, 0, 1);
    const half8 b10 = load_bfrag(W1, lane, 1, 0), b11 = load_bfrag(W1, lane, 1, 1);
    const half8 b20 = load_bfrag(W1, lane, 2, 0), b21 = load_bfrag(W1, lane, 2, 1);
    const half8 b30 = load_bfrag(W1, lane, 3, 0), b31 = load_bfrag(W1, lane, 3, 1);
    const float bias0 = b1[(lane & 15) +  0], bias1 = b1[(lane & 15) + 16];
    const float bias2 = b1[(lane & 15) + 32], bias3 = b1[(lane & 15) + 48];

    float ps0 = 0.f, ps1 = 0.f, ps2 = 0.f, ps3 = 0.f;
    float pq0 = 0.f, pq1 = 0.f, pq2 = 0.f, pq3 = 0.f;

#pragma unroll
    for (int t = 0; t < TPW; ++t) {
        const int tb = rbase + t * 16;
        // --- gather + max-pool 16 rows (4 groups of 4), f16 -> LDS ---
#pragma unroll
        for (int s = 0; s < 4; ++s) {
            const int r4 = tb + s * 4;
            const int mi = idxs[(size_t)r4 * KK + lane];   // 4 rows x 16 idx
            const float p0 = gmax16(cfb, mi,  0, lane);
            const float p1 = gmax16(cfb, mi, 16, lane);
            const float p2 = gmax16(cfb, mi, 32, lane);
            const float p3 = gmax16(cfb, mi, 48, lane);
            ah[wv][s * 4 + 0][lane] = (_Float16)p0;
            ah[wv][s * 4 + 1][lane] = (_Float16)p1;
            ah[wv][s * 4 + 2][lane] = (_Float16)p2;
            ah[wv][s * 4 + 3][lane] = (_Float16)p3;
            if (lane < 3) {
                out[(size_t)(r4 + 0) * OUTW + lane] = scoord[(size_t)(r4 + 0) * 3 + lane];
                out[(size_t)(r4 + 1) * OUTW + lane] = scoord[(size_t)(r4 + 1) * 3 + lane];
                out[(size_t)(r4 + 2) * OUTW + lane] = scoord[(size_t)(r4 + 2) * 3 + lane];
                out[(size_t)(r4 + 3) * OUTW + lane] = scoord[(size_t)(r4 + 3) * 3 + lane];
            }
        }
        __builtin_amdgcn_wave_barrier();

        // --- A-fragments: row = lane&15, k = (lane>>4)*8 + j (+32 for kt=1) ---
        const half8 a0 = *(const half8*)&ah[wv][lane & 15][((lane >> 4) << 3)];
        const half8 a1 = *(const half8*)&ah[wv][lane & 15][32 + ((lane >> 4) << 3)];

        f32x4 ac0 = {0.f, 0.f, 0.f, 0.f}, ac1 = ac0, ac2 = ac0, ac3 = ac0;
        ac0 = MFMA16(a0, b00, ac0); ac0 = MFMA16(a1, b01, ac0);
        ac1 = MFMA16(a0, b10, ac1); ac1 = MFMA16(a1, b11, ac1);
        ac2 = MFMA16(a0, b20, ac2); ac2 = MFMA16(a1, b21, ac2);
        ac3 = MFMA16(a0, b30, ac3); ac3 = MFMA16(a1, b31, ac3);
        __builtin_amdgcn_wave_barrier();

        // --- epilogue: y = acc + bias; store raw y; accumulate stats ---
        // C layout (HW-verified): col = lane&15, row = (lane>>4)*4 + j
        const int rl = tb + ((lane >> 4) << 2);
        const int cl = lane & 15;
#pragma unroll
        for (int j = 0; j < 4; ++j) {
            const size_t ob = (size_t)(rl + j) * OUTW + 3 + cl;
            const float y0 = ac0[j] + bias0;
            const float y1 = ac1[j] + bias1;
            const float y2 = ac2[j] + bias2;
            const float y3 = ac3[j] + bias3;
            out[ob +  0] = y0;
            out[ob + 16] = y1;
            out[ob + 32] = y2;
            out[ob + 48] = y3;
            ps0 += y0; pq0 += y0 * y0;
            ps1 += y1; pq1 += y1 * y1;
            ps2 += y2; pq2 += y2 * y2;
            ps3 += y3; pq3 += y3 * y3;
        }
    }

    atomicAdd(&lsum[(lane & 15) +  0], ps0); atomicAdd(&lsq[(lane & 15) +  0], pq0);
    atomicAdd(&lsum[(lane & 15) + 16], ps1); atomicAdd(&lsq[(lane & 15) + 16], pq1);
    atomicAdd(&lsum[(lane & 15) + 32], ps2); atomicAdd(&lsq[(lane & 15) + 32], pq2);
    atomicAdd(&lsum[(lane & 15) + 48], ps3); atomicAdd(&lsq[(lane & 15) + 48], pq3);
    __syncthreads();
    if (threadIdx.x < 64) {
        atomicAdd(&acc[threadIdx.x],      lsum[threadIdx.x]);
        atomicAdd(&acc[64 + threadIdx.x], lsq[threadIdx.x]);
    }
}

// ---------------------------------------------------------------------------
// Kernel 2: (skip_feat @ W2 + b2) via MFMA -> out[..., 67:131]
//           per-channel sum/sumsq -> ws[128:256]
// ---------------------------------------------------------------------------
__global__ __launch_bounds__(256) void k_skip_proj(
    const float* __restrict__ sf,
    const float* __restrict__ W2, const float* __restrict__ b2,
    float* __restrict__ out, float* __restrict__ acc)
{
    __shared__ _Float16 ah[4][16][APAD];
    __shared__ float lsum[64], lsq[64];
    const int lane = threadIdx.x & 63;
    const int wv   = threadIdx.x >> 6;
    if (threadIdx.x < 64) { lsum[threadIdx.x] = 0.f; lsq[threadIdx.x] = 0.f; }
    __syncthreads();

    const int rbase = (blockIdx.x * 4 + wv) * RPWAVE;

    const half8 b00 = load_bfrag(W2, lane, 0, 0), b01 = load_bfrag(W2, lane, 0, 1);
    const half8 b10 = load_bfrag(W2, lane, 1, 0), b11 = load_bfrag(W2, lane, 1, 1);
    const half8 b20 = load_bfrag(W2, lane, 2, 0), b21 = load_bfrag(W2, lane, 2, 1);
    const half8 b30 = load_bfrag(W2, lane, 3, 0), b31 = load_bfrag(W2, lane, 3, 1);
    const float bias0 = b2[(lane & 15) +  0], bias1 = b2[(lane & 15) + 16];
    const float bias2 = b2[(lane & 15) + 32], bias3 = b2[(lane & 15) + 48];

    float ps0 = 0.f, ps1 = 0.f, ps2 = 0.f, ps3 = 0.f;
    float pq0 = 0.f, pq1 = 0.f, pq2 = 0.f, pq3 = 0.f;

#pragma unroll
    for (int t = 0; t < TPW; ++t) {
        const int tb = rbase + t * 16;
#pragma unroll
        for (int s = 0; s < 4; ++s) {
            const int r4 = tb + s * 4;
            const float x0 = sf[(size_t)(r4 + 0) * 64 + lane];
            const float x1 = sf[(size_t)(r4 + 1) * 64 + lane];
            const float x2 = sf[(size_t)(r4 + 2) * 64 + lane];
            const float x3 = sf[(size_t)(r4 + 3) * 64 + lane];
            ah[wv][s * 4 + 0][lane] = (_Float16)x0;
            ah[wv][s * 4 + 1][lane] = (_Float16)x1;
            ah[wv][s * 4 + 2][lane] = (_Float16)x2;
            ah[wv][s * 4 + 3][lane] = (_Float16)x3;
        }
        __builtin_amdgcn_wave_barrier();

        const half8 a0 = *(const half8*)&ah[wv][lane & 15][((lane >> 4) << 3)];
        const half8 a1 = *(const half8*)&ah[wv][lane & 15][32 + ((lane >> 4) << 3)];

        f32x4 ac0 = {0.f, 0.f, 0.f, 0.f}, ac1 = ac0, ac2 = ac0, ac3 = ac0;
        ac0 = MFMA16(a0, b00, ac0); ac0 = MFMA16(a1, b01, ac0);
        ac1 = MFMA16(a0, b10, ac1); ac1 = MFMA16(a1, b11, ac1);
        ac2 = MFMA16(a0, b20, ac2); ac2 = MFMA16(a1, b21, ac2);
        ac3 = MFMA16(a0, b30, ac3); ac3 = MFMA16(a1, b31, ac3);
        __builtin_amdgcn_wave_barrier();

        const int rl = tb + ((lane >> 4) << 2);
        const int cl = lane & 15;
#pragma unroll
        for (int j = 0; j < 4; ++j) {
            const size_t ob = (size_t)(rl + j) * OUTW + 67 + cl;
            const float y0 = ac0[j] + bias0;
            const float y1 = ac1[j] + bias1;
            const float y2 = ac2[j] + bias2;
            const float y3 = ac3[j] + bias3;
            out[ob +  0] = y0;
            out[ob + 16] = y1;
            out[ob + 32] = y2;
            out[ob + 48] = y3;
            ps0 += y0; pq0 += y0 * y0;
            ps1 += y1; pq1 += y1 * y1;
            ps2 += y2; pq2 += y2 * y2;
            ps3 += y3; pq3 += y3 * y3;
        }
    }

    atomicAdd(&lsum[(lane & 15) +  0], ps0); atomicAdd(&lsq[(lane & 15) +  0], pq0);
    atomicAdd(&lsum[(lane & 15) + 16], ps1); atomicAdd(&lsq[(lane & 15) + 16], pq1);
    atomicAdd(&lsum[(lane & 15) + 32], ps2); atomicAdd(&lsq[(lane & 15) + 32], pq2);
    atomicAdd(&lsum[(lane & 15) + 48], ps3); atomicAdd(&lsq[(lane & 15) + 48], pq3);
    __syncthreads();
    if (threadIdx.x < 64) {
        atomicAdd(&acc[128 + threadIdx.x], lsum[threadIdx.x]);
        atomicAdd(&acc[192 + threadIdx.x], lsq[threadIdx.x]);
    }
}

// ---------------------------------------------------------------------------
// Kernel 3: fold sums -> affine params  a = g*rsqrt(var+eps), c = beta - mu*a
// ws layout: [0:64] sum1 [64:128] sq1 [128:192] sum2 [192:256] sq2
//            [256:384] a (a1|a2)  [384:512] c (c1|c2)
// ---------------------------------------------------------------------------
__global__ void k_stats(float* __restrict__ ws,
                        const float* __restrict__ g1, const float* __restrict__ be1,
                        const float* __restrict__ g2, const float* __restrict__ be2)
{
    const int o = threadIdx.x;  // 64 threads
    const float inv = 1.0f / (float)ROWS;
    float m1 = ws[o] * inv;
    float v1 = ws[64 + o] * inv - m1 * m1;
    float a1 = g1[o] * rsqrtf(v1 + 1e-5f);
    ws[256 + o] = a1;
    ws[384 + o] = be1[o] - m1 * a1;
    float m2 = ws[128 + o] * inv;
    float v2 = ws[192 + o] * inv - m2 * m2;
    float a2 = g2[o] * rsqrtf(v2 + 1e-5f);
    ws[256 + 64 + o] = a2;
    ws[384 + 64 + o] = be2[o] - m2 * a2;
}

// ---------------------------------------------------------------------------
// Kernel 4: in-place  out[r*131 + 3 + j] = relu(a[j]*y + c[j]),  j in [0,128)
// ---------------------------------------------------------------------------
__global__ __launch_bounds__(256) void k_finalize(float* __restrict__ out,
                                                  const float* __restrict__ ws)
{
    const size_t T  = (size_t)gridDim.x * blockDim.x;
    const size_t t0 = (size_t)blockIdx.x * blockDim.x + threadIdx.x;
#pragma unroll
    for (int i = 0; i < 4; ++i) {
        const size_t e = t0 + (size_t)i * T;       // e < ROWS*128
        const size_t r = e >> 7;
        const int    j = (int)(e & 127);
        const size_t ad = r * OUTW + 3 + j;
        const float v = out[ad];
        out[ad] = fmaxf(fmaf(v, ws[256 + j], ws[384 + j]), 0.f);
    }
}

// ---------------------------------------------------------------------------
extern "C" void kernel_launch(void* const* d_in, const int* in_sizes, int n_in,
                              void* d_out, int out_size, void* d_ws, size_t ws_size,
                              hipStream_t stream)
{
    const float* cf     = (const float*)d_in[1];   // curr_feat (B,M,64)
    const float* scoord = (const float*)d_in[2];   // skip_coords (B,N,3)
    const float* sf     = (const float*)d_in[3];   // skip_feat (B,N,64)
    const int*   idxs   = (const int*)  d_in[4];   // upsampling_idxs (B,N,16)
    const float* W1     = (const float*)d_in[5];
    const float* b1     = (const float*)d_in[6];
    const float* g1     = (const float*)d_in[7];
    const float* be1    = (const float*)d_in[8];
    const float* W2     = (const float*)d_in[9];
    const float* b2     = (const float*)d_in[10];
    const float* g2     = (const float*)d_in[11];
    const float* be2    = (const float*)d_in[12];
    float* out = (float*)d_out;
    float* ws  = (float*)d_ws;

    hipMemsetAsync(ws, 0, 256 * sizeof(float), stream);  // zero the accumulators
    k_pool_proj<<<A_BLOCKS, 256, 0, stream>>>(cf, idxs, scoord, W1, b1, out, ws);
    k_skip_proj<<<A_BLOCKS, 256, 0, stream>>>(sf, W2, b2, out, ws);
    k_stats<<<1, 64, 0, stream>>>(ws, g1, be1, g2, be2);
    // ROWS*128 = 16,777,216 elements; 16384 blocks * 256 threads * 4 elems
    k_finalize<<<16384, 256, 0, stream>>>(out, ws);
}

// Round 7
// 293.410 us; speedup vs baseline: 1.0833x; 1.0833x over previous
//
#include <hip/hip_runtime.h>

// Problem constants (from reference setup_inputs)
#define BB 4
#define MM 16384
#define NN 32768
#define KK 16
#define ROWS (BB * NN)   // 131072
#define OUTW 131         // 3 coords + 64 + 64
#define TROWS 16         // rows per wave (one MFMA tile)
#define A_BLOCKS (ROWS / (TROWS * 4))   // 2048 blocks, 4 waves each
#define APAD 72          // padded k-stride of LDS A-tile in f16 (144B row: b128-aligned, 2-way free)

// Lessons encoded:
//  r1-r3: NO runtime-indexed per-thread arrays (scratch demotion -> GBs of HBM).
//  r1/r4: XCD swizzle validated (FETCH 211->67 MB).
//  r4:    VALU inner product was the bottleneck -> MFMA (r5, validated correct).
//  r5:    MFMA alone went latency-bound (occ 21%, all pipes idle): grid was
//         halved and 256 gather loads drain before each MFMA. This round:
//         2048 blocks again + half-wave float2 gather (2 rows per wave-load).
//  r6:    container-level infra failure (no counters); source audited clean
//         (no OOB / no hang / alignment ok) -> resubmit unchanged algorithm.

typedef _Float16 half8  __attribute__((ext_vector_type(8)));
typedef _Float16 half2v __attribute__((ext_vector_type(2)));
typedef float f32x4 __attribute__((ext_vector_type(4)));

#define MFMA16(a, b, c) __builtin_amdgcn_mfma_f32_16x16x32_f16(a, b, c, 0, 0, 0)

// B-fragment (32x16 of W, f16): lane holds k = kt*32 + (lane>>4)*8 + j, col = ot*16 + (lane&15)
__device__ __forceinline__ half8 load_bfrag(const float* __restrict__ W, int lane, int ot, int kt) {
    const int kb  = kt * 32 + ((lane >> 4) << 3);
    const int col = ot * 16 + (lane & 15);
    half8 b;
#pragma unroll
    for (int j = 0; j < 8; ++j) b[j] = (_Float16)W[(kb + j) * 64 + col];
    return b;
}

// Gather+max one ROW-PAIR: lanes<32 own row (sub), lanes>=32 own row (sub+1),
// each lane holds channels 2*(lane&31), +1 as float2. One dwordx2 wave-load
// covers both rows' k-th neighbor. Index for this lane's row via ds_bpermute.
// pb = (sub + (lane>>5)) * 64  (bpermute byte index base into mi)
__device__ __forceinline__ half2v gpair(const float* __restrict__ cfb, int mi, int pb, int coff) {
    float q0x = -3.402823466e38f, q0y = q0x, q1x = q0x, q1y = q0x;
#pragma unroll
    for (int k = 0; k < KK; k += 2) {
        const int m0 = __builtin_amdgcn_ds_bpermute(pb + (k << 2), mi);
        const int m1 = __builtin_amdgcn_ds_bpermute(pb + ((k + 1) << 2), mi);
        const float2 v0 = *(const float2*)&cfb[((size_t)m0 << 6) + coff];
        const float2 v1 = *(const float2*)&cfb[((size_t)m1 << 6) + coff];
        q0x = fmaxf(q0x, v0.x); q0y = fmaxf(q0y, v0.y);
        q1x = fmaxf(q1x, v1.x); q1y = fmaxf(q1y, v1.y);
    }
    half2v h;
    h[0] = (_Float16)fmaxf(q0x, q1x);
    h[1] = (_Float16)fmaxf(q0y, q1y);
    return h;
}

// ---------------------------------------------------------------------------
// Kernel 1: gather + max-pool + (pooled @ W1 + b1) via MFMA -> out[..., 3:67]
//           + coords -> out[..., 0:3]; per-channel sum/sumsq -> ws[0:128]
// ---------------------------------------------------------------------------
__global__ __launch_bounds__(256) void k_pool_proj(
    const float* __restrict__ cf, const int* __restrict__ idxs,
    const float* __restrict__ scoord,
    const float* __restrict__ W1, const float* __restrict__ b1,
    float* __restrict__ out, float* __restrict__ acc)
{
    __shared__ _Float16 ah[4][TROWS][APAD];   // per-wave 16x64 f16 A-tile
    __shared__ float lsum[64], lsq[64];
    const int lane = threadIdx.x & 63;
    const int wv   = threadIdx.x >> 6;
    if (threadIdx.x < 64) { lsum[threadIdx.x] = 0.f; lsq[threadIdx.x] = 0.f; }
    __syncthreads();

    // XCD swizzle (validated): block w -> XCD w&7; each batch owns 2 XCDs so
    // its 4.2 MB cf slice stays L2-resident.
    const int w     = blockIdx.x;
    const int xcd   = w & 7;
    const int batch = xcd >> 1;
    const int lb    = (w >> 3) + ((xcd & 1) << 8);   // [0,512) slots per batch
    const int rbase = batch * NN + (lb * 4 + wv) * TROWS;
    const float* cfb = cf + ((size_t)batch << 20);

    // W1 fragments in registers (32 VGPRs), loaded once
    const half8 b00 = load_bfrag(W1, lane, 0, 0), b01 = load_bfrag(W1, lane, 0, 1);
    const half8 b10 = load_bfrag(W1, lane, 1, 0), b11 = load_bfrag(W1, lane, 1, 1);
    const half8 b20 = load_bfrag(W1, lane, 2, 0), b21 = load_bfrag(W1, lane, 2, 1);
    const half8 b30 = load_bfrag(W1, lane, 3, 0), b31 = load_bfrag(W1, lane, 3, 1);
    const float bias0 = b1[(lane & 15) +  0], bias1 = b1[(lane & 15) + 16];
    const float bias2 = b1[(lane & 15) + 32], bias3 = b1[(lane & 15) + 48];

    // index loads for all 16 rows (4 rows x 16 idx each), issued upfront
    const int mi0 = idxs[(size_t)(rbase +  0) * KK + lane];
    const int mi1 = idxs[(size_t)(rbase +  4) * KK + lane];
    const int mi2 = idxs[(size_t)(rbase +  8) * KK + lane];
    const int mi3 = idxs[(size_t)(rbase + 12) * KK + lane];

    // coords: 16 rows x 3 = 48 contiguous floats, coalesced read
    if (lane < 48) {
        const float cv = scoord[(size_t)rbase * 3 + lane];
        const int rr = lane / 3;
        out[(size_t)(rbase + rr) * OUTW + (lane - rr * 3)] = cv;
    }

    const int rr   = lane >> 5;          // which row of each pair
    const int coff = (lane & 31) << 1;   // channel pair
    const int pb0  = (0 + rr) << 6;      // bpermute base for sub=0
    const int pb2  = (2 + rr) << 6;      // bpermute base for sub=2

    *(half2v*)&ah[wv][ 0 + rr][coff] = gpair(cfb, mi0, pb0, coff);
    *(half2v*)&ah[wv][ 2 + rr][coff] = gpair(cfb, mi0, pb2, coff);
    *(half2v*)&ah[wv][ 4 + rr][coff] = gpair(cfb, mi1, pb0, coff);
    *(half2v*)&ah[wv][ 6 + rr][coff] = gpair(cfb, mi1, pb2, coff);
    *(half2v*)&ah[wv][ 8 + rr][coff] = gpair(cfb, mi2, pb0, coff);
    *(half2v*)&ah[wv][10 + rr][coff] = gpair(cfb, mi2, pb2, coff);
    *(half2v*)&ah[wv][12 + rr][coff] = gpair(cfb, mi3, pb0, coff);
    *(half2v*)&ah[wv][14 + rr][coff] = gpair(cfb, mi3, pb2, coff);
    __builtin_amdgcn_wave_barrier();

    // A-fragments: row = lane&15, k = (lane>>4)*8 + j (+32 for the second)
    const half8 a0 = *(const half8*)&ah[wv][lane & 15][((lane >> 4) << 3)];
    const half8 a1 = *(const half8*)&ah[wv][lane & 15][32 + ((lane >> 4) << 3)];

    f32x4 ac0 = {0.f, 0.f, 0.f, 0.f}, ac1 = ac0, ac2 = ac0, ac3 = ac0;
    ac0 = MFMA16(a0, b00, ac0); ac0 = MFMA16(a1, b01, ac0);
    ac1 = MFMA16(a0, b10, ac1); ac1 = MFMA16(a1, b11, ac1);
    ac2 = MFMA16(a0, b20, ac2); ac2 = MFMA16(a1, b21, ac2);
    ac3 = MFMA16(a0, b30, ac3); ac3 = MFMA16(a1, b31, ac3);
    __builtin_amdgcn_wave_barrier();

    // epilogue: y = acc + bias; raw y out; stats. C layout: col=lane&15, row=(lane>>4)*4+j
    float ps0 = 0.f, ps1 = 0.f, ps2 = 0.f, ps3 = 0.f;
    float pq0 = 0.f, pq1 = 0.f, pq2 = 0.f, pq3 = 0.f;
    const int rl = rbase + ((lane >> 4) << 2);
    const int cl = lane & 15;
#pragma unroll
    for (int j = 0; j < 4; ++j) {
        const size_t ob = (size_t)(rl + j) * OUTW + 3 + cl;
        const float y0 = ac0[j] + bias0;
        const float y1 = ac1[j] + bias1;
        const float y2 = ac2[j] + bias2;
        const float y3 = ac3[j] + bias3;
        out[ob +  0] = y0;
        out[ob + 16] = y1;
        out[ob + 32] = y2;
        out[ob + 48] = y3;
        ps0 += y0; pq0 += y0 * y0;
        ps1 += y1; pq1 += y1 * y1;
        ps2 += y2; pq2 += y2 * y2;
        ps3 += y3; pq3 += y3 * y3;
    }

    atomicAdd(&lsum[cl +  0], ps0); atomicAdd(&lsq[cl +  0], pq0);
    atomicAdd(&lsum[cl + 16], ps1); atomicAdd(&lsq[cl + 16], pq1);
    atomicAdd(&lsum[cl + 32], ps2); atomicAdd(&lsq[cl + 32], pq2);
    atomicAdd(&lsum[cl + 48], ps3); atomicAdd(&lsq[cl + 48], pq3);
    __syncthreads();
    if (threadIdx.x < 64) {
        atomicAdd(&acc[threadIdx.x],      lsum[threadIdx.x]);
        atomicAdd(&acc[64 + threadIdx.x], lsq[threadIdx.x]);
    }
}

// ---------------------------------------------------------------------------
// Kernel 2: (skip_feat @ W2 + b2) via MFMA -> out[..., 67:131]
// No LDS: each lane loads its A-fragment directly from sf (4x float4 -> f16).
// ---------------------------------------------------------------------------
__global__ __launch_bounds__(256) void k_skip_proj(
    const float* __restrict__ sf,
    const float* __restrict__ W2, const float* __restrict__ b2,
    float* __restrict__ out, float* __restrict__ acc)
{
    __shared__ float lsum[64], lsq[64];
    const int lane = threadIdx.x & 63;
    const int wv   = threadIdx.x >> 6;
    if (threadIdx.x < 64) { lsum[threadIdx.x] = 0.f; lsq[threadIdx.x] = 0.f; }
    __syncthreads();

    const int tb = (blockIdx.x * 4 + wv) * TROWS;

    const half8 b00 = load_bfrag(W2, lane, 0, 0), b01 = load_bfrag(W2, lane, 0, 1);
    const half8 b10 = load_bfrag(W2, lane, 1, 0), b11 = load_bfrag(W2, lane, 1, 1);
    const half8 b20 = load_bfrag(W2, lane, 2, 0), b21 = load_bfrag(W2, lane, 2, 1);
    const half8 b30 = load_bfrag(W2, lane, 3, 0), b31 = load_bfrag(W2, lane, 3, 1);
    const float bias0 = b2[(lane & 15) +  0], bias1 = b2[(lane & 15) + 16];
    const float bias2 = b2[(lane & 15) + 32], bias3 = b2[(lane & 15) + 48];

    // A-fragment direct from global: row = tb + (lane&15), k-base = (lane>>4)*8
    const size_t ab = (size_t)(tb + (lane & 15)) * 64 + ((lane >> 4) << 3);
    const float4 f0 = *(const float4*)&sf[ab +  0];
    const float4 f1 = *(const float4*)&sf[ab +  4];
    const float4 f2 = *(const float4*)&sf[ab + 32];
    const float4 f3 = *(const float4*)&sf[ab + 36];
    const half8 a0 = {(_Float16)f0.x, (_Float16)f0.y, (_Float16)f0.z, (_Float16)f0.w,
                      (_Float16)f1.x, (_Float16)f1.y, (_Float16)f1.z, (_Float16)f1.w};
    const half8 a1 = {(_Float16)f2.x, (_Float16)f2.y, (_Float16)f2.z, (_Float16)f2.w,
                      (_Float16)f3.x, (_Float16)f3.y, (_Float16)f3.z, (_Float16)f3.w};

    f32x4 ac0 = {0.f, 0.f, 0.f, 0.f}, ac1 = ac0, ac2 = ac0, ac3 = ac0;
    ac0 = MFMA16(a0, b00, ac0); ac0 = MFMA16(a1, b01, ac0);
    ac1 = MFMA16(a0, b10, ac1); ac1 = MFMA16(a1, b11, ac1);
    ac2 = MFMA16(a0, b20, ac2); ac2 = MFMA16(a1, b21, ac2);
    ac3 = MFMA16(a0, b30, ac3); ac3 = MFMA16(a1, b31, ac3);

    float ps0 = 0.f, ps1 = 0.f, ps2 = 0.f, ps3 = 0.f;
    float pq0 = 0.f, pq1 = 0.f, pq2 = 0.f, pq3 = 0.f;
    const int rl = tb + ((lane >> 4) << 2);
    const int cl = lane & 15;
#pragma unroll
    for (int j = 0; j < 4; ++j) {
        const size_t ob = (size_t)(rl + j) * OUTW + 67 + cl;
        const float y0 = ac0[j] + bias0;
        const float y1 = ac1[j] + bias1;
        const float y2 = ac2[j] + bias2;
        const float y3 = ac3[j] + bias3;
        out[ob +  0] = y0;
        out[ob + 16] = y1;
        out[ob + 32] = y2;
        out[ob + 48] = y3;
        ps0 += y0; pq0 += y0 * y0;
        ps1 += y1; pq1 += y1 * y1;
        ps2 += y2; pq2 += y2 * y2;
        ps3 += y3; pq3 += y3 * y3;
    }

    atomicAdd(&lsum[cl +  0], ps0); atomicAdd(&lsq[cl +  0], pq0);
    atomicAdd(&lsum[cl + 16], ps1); atomicAdd(&lsq[cl + 16], pq1);
    atomicAdd(&lsum[cl + 32], ps2); atomicAdd(&lsq[cl + 32], pq2);
    atomicAdd(&lsum[cl + 48], ps3); atomicAdd(&lsq[cl + 48], pq3);
    __syncthreads();
    if (threadIdx.x < 64) {
        atomicAdd(&acc[128 + threadIdx.x], lsum[threadIdx.x]);
        atomicAdd(&acc[192 + threadIdx.x], lsq[threadIdx.x]);
    }
}

// ---------------------------------------------------------------------------
// Kernel 3: fold sums -> affine params  a = g*rsqrt(var+eps), c = beta - mu*a
// ws layout: [0:64] sum1 [64:128] sq1 [128:192] sum2 [192:256] sq2
//            [256:384] a (a1|a2)  [384:512] c (c1|c2)
// ---------------------------------------------------------------------------
__global__ void k_stats(float* __restrict__ ws,
                        const float* __restrict__ g1, const float* __restrict__ be1,
                        const float* __restrict__ g2, const float* __restrict__ be2)
{
    const int o = threadIdx.x;  // 64 threads
    const float inv = 1.0f / (float)ROWS;
    float m1 = ws[o] * inv;
    float v1 = ws[64 + o] * inv - m1 * m1;
    float a1 = g1[o] * rsqrtf(v1 + 1e-5f);
    ws[256 + o] = a1;
    ws[384 + o] = be1[o] - m1 * a1;
    float m2 = ws[128 + o] * inv;
    float v2 = ws[192 + o] * inv - m2 * m2;
    float a2 = g2[o] * rsqrtf(v2 + 1e-5f);
    ws[256 + 64 + o] = a2;
    ws[384 + 64 + o] = be2[o] - m2 * a2;
}

// ---------------------------------------------------------------------------
// Kernel 4: in-place  out[r*131 + 3 + j] = relu(a[j]*y + c[j]),  j in [0,128)
// ---------------------------------------------------------------------------
__global__ __launch_bounds__(256) void k_finalize(float* __restrict__ out,
                                                  const float* __restrict__ ws)
{
    const size_t T  = (size_t)gridDim.x * blockDim.x;
    const size_t t0 = (size_t)blockIdx.x * blockDim.x + threadIdx.x;
#pragma unroll
    for (int i = 0; i < 4; ++i) {
        const size_t e = t0 + (size_t)i * T;       // e < ROWS*128
        const size_t r = e >> 7;
        const int    j = (int)(e & 127);
        const size_t ad = r * OUTW + 3 + j;
        const float v = out[ad];
        out[ad] = fmaxf(fmaf(v, ws[256 + j], ws[384 + j]), 0.f);
    }
}

// ---------------------------------------------------------------------------
extern "C" void kernel_launch(void* const* d_in, const int* in_sizes, int n_in,
                              void* d_out, int out_size, void* d_ws, size_t ws_size,
                              hipStream_t stream)
{
    const float* cf     = (const float*)d_in[1];   // curr_feat (B,M,64)
    const float* scoord = (const float*)d_in[2];   // skip_coords (B,N,3)
    const float* sf     = (const float*)d_in[3];   // skip_feat (B,N,64)
    const int*   idxs   = (const int*)  d_in[4];   // upsampling_idxs (B,N,16)
    const float* W1     = (const float*)d_in[5];
    const float* b1     = (const float*)d_in[6];
    const float* g1     = (const float*)d_in[7];
    const float* be1    = (const float*)d_in[8];
    const float* W2     = (const float*)d_in[9];
    const float* b2     = (const float*)d_in[10];
    const float* g2     = (const float*)d_in[11];
    const float* be2    = (const float*)d_in[12];
    float* out = (float*)d_out;
    float* ws  = (float*)d_ws;

    hipMemsetAsync(ws, 0, 256 * sizeof(float), stream);  // zero the accumulators
    k_pool_proj<<<A_BLOCKS, 256, 0, stream>>>(cf, idxs, scoord, W1, b1, out, ws);
    k_skip_proj<<<A_BLOCKS, 256, 0, stream>>>(sf, W2, b2, out, ws);
    k_stats<<<1, 64, 0, stream>>>(ws, g1, be1, g2, be2);
    // ROWS*128 = 16,777,216 elements; 16384 blocks * 256 threads * 4 elems
    k_finalize<<<16384, 256, 0, stream>>>(out, ws);
}

// Round 9
// 275.234 us; speedup vs baseline: 1.1549x; 1.0660x over previous
//
#include <hip/hip_runtime.h>

// Problem constants (from reference setup_inputs)
#define BB 4
#define MM 16384
#define NN 32768
#define KK 16
#define ROWS (BB * NN)   // 131072
#define OUTW 131         // 3 coords + 64 + 64
#define TROWS 16         // rows per wave (one MFMA tile)
#define A_BLOCKS (ROWS / (TROWS * 4))   // 2048 blocks, 4 waves each
#define APAD 72          // padded k-stride of LDS A-tile in f16 units (144B rows)
#define CFH_BYTES ((size_t)BB * MM * 64 * 2)   // 8,388,608

// Lessons encoded:
//  r1-r3: NO runtime-indexed per-thread arrays (scratch demotion -> GBs of HBM).
//  r1/r4: XCD swizzle validated (FETCH 211->67 MB).
//  r4/r5: VALU inner product -> MFMA (validated correct, r5/r7).
//  r0/r4/r7: k_pool_proj pinned at ~93 us across 3 structurally different
//         kernels. Invariant = 2M random 256B row reads -> line-request bound.
//  r8:    __hmax2 doesn't exist in ROCm 7.2 hip_fp16.h -> compile fail.
//         THIS ROUND: same algorithm, _Float16 vectors + inline-asm
//         v_pk_max_f16 (no hip_fp16.h dependency).

typedef _Float16 half8 __attribute__((ext_vector_type(8)));
typedef _Float16 h2    __attribute__((ext_vector_type(2)));
typedef float f32x4 __attribute__((ext_vector_type(4)));

#define MFMA16(a, b, c) __builtin_amdgcn_mfma_f32_16x16x32_f16(a, b, c, 0, 0, 0)

// packed f16 max on a 32-bit word (2 halves) — gfx950 v_pk_max_f16
__device__ __forceinline__ unsigned pkmax(unsigned a, unsigned b) {
    unsigned r;
    asm("v_pk_max_f16 %0, %1, %2" : "=v"(r) : "v"(a), "v"(b));
    return r;
}

// B-fragment (32x16 of W, f16): lane holds k = kt*32 + (lane>>4)*8 + j, col = ot*16 + (lane&15)
__device__ __forceinline__ half8 load_bfrag(const float* __restrict__ W, int lane, int ot, int kt) {
    const int kb  = kt * 32 + ((lane >> 4) << 3);
    const int col = ot * 16 + (lane & 15);
    half8 b;
#pragma unroll
    for (int j = 0; j < 8; ++j) b[j] = (_Float16)W[(kb + j) * 64 + col];
    return b;
}

// ---------------------------------------------------------------------------
// Kernel 0: cf (f32) -> cfh (f16), streaming. 1,048,576 float4 -> 4x f16
// ---------------------------------------------------------------------------
__global__ __launch_bounds__(256) void k_half(const float* __restrict__ cf,
                                              _Float16* __restrict__ cfh)
{
    const int i = blockIdx.x * 256 + threadIdx.x;   // < 1,048,576
    const float4 v = ((const float4*)cf)[i];
    union { h2 h[2]; float2 f; } u;
    u.h[0] = h2{(_Float16)v.x, (_Float16)v.y};
    u.h[1] = h2{(_Float16)v.z, (_Float16)v.w};
    ((float2*)cfh)[i] = u.f;
}

// ---------------------------------------------------------------------------
// Kernel 1 (f16 path): gather + max-pool + (pooled @ W1 + b1) via MFMA
//   -> out[..., 3:67]; coords -> out[..., 0:3]; sum/sumsq -> ws[0:128]
// Gather: lane = (rr = lane>>4 row-of-4, q = lane&15 channel-quad).
// One 8B load covers 4 channels of one f16 row; one wave-load covers 4 rows.
// 64 loads + 64 bpermutes per 16-row tile (r7 had 128+128 on 256B rows).
// ---------------------------------------------------------------------------
__global__ __launch_bounds__(256) void k_pool_proj_h(
    const _Float16* __restrict__ cfh, const int* __restrict__ idxs,
    const float* __restrict__ scoord,
    const float* __restrict__ W1, const float* __restrict__ b1,
    float* __restrict__ out, float* __restrict__ acc)
{
    __shared__ _Float16 ah[4][TROWS][APAD];   // per-wave 16x64 f16 A-tile
    __shared__ float lsum[64], lsq[64];
    const int lane = threadIdx.x & 63;
    const int wv   = threadIdx.x >> 6;
    if (threadIdx.x < 64) { lsum[threadIdx.x] = 0.f; lsq[threadIdx.x] = 0.f; }
    __syncthreads();

    // XCD swizzle (validated): block w -> XCD w&7; each batch owns 2 XCDs.
    const int w     = blockIdx.x;
    const int xcd   = w & 7;
    const int batch = xcd >> 1;
    const int lb    = (w >> 3) + ((xcd & 1) << 8);   // [0,512) slots per batch
    const int rbase = batch * NN + (lb * 4 + wv) * TROWS;
    const _Float16* cfb = cfh + ((size_t)batch << 20);

    const half8 b00 = load_bfrag(W1, lane, 0, 0), b01 = load_bfrag(W1, lane, 0, 1);
    const half8 b10 = load_bfrag(W1, lane, 1, 0), b11 = load_bfrag(W1, lane, 1, 1);
    const half8 b20 = load_bfrag(W1, lane, 2, 0), b21 = load_bfrag(W1, lane, 2, 1);
    const half8 b30 = load_bfrag(W1, lane, 3, 0), b31 = load_bfrag(W1, lane, 3, 1);
    const float bias0 = b1[(lane & 15) +  0], bias1 = b1[(lane & 15) + 16];
    const float bias2 = b1[(lane & 15) + 32], bias3 = b1[(lane & 15) + 48];

    // indices for 16 rows: mi_g covers rows 4g..4g+3 (lane = row_in_g*16 + k)
    const int mi0 = idxs[(size_t)(rbase +  0) * KK + lane];
    const int mi1 = idxs[(size_t)(rbase +  4) * KK + lane];
    const int mi2 = idxs[(size_t)(rbase +  8) * KK + lane];
    const int mi3 = idxs[(size_t)(rbase + 12) * KK + lane];

    // coords: 16 rows x 3 = 48 contiguous floats
    if (lane < 48) {
        const float cv = scoord[(size_t)rbase * 3 + lane];
        const int rj = lane / 3;
        out[(size_t)(rbase + rj) * OUTW + (lane - rj * 3)] = cv;
    }

    const int rr = lane >> 4;        // row within group of 4
    const int qc = (lane & 15) << 2; // channel offset (quad of halves)
    const int pb = rr << 6;          // bpermute byte base: source lane = rr*16 + k

    // gather+max one group of 4 rows; row = g*4+rr, f16 row stride = 64 halves
#define GATHER_G(mi, g) do {                                                   \
        const int m0 = __builtin_amdgcn_ds_bpermute(pb, mi);                   \
        uint2 u0 = *(const uint2*)&cfb[((size_t)m0 << 6) + qc];                \
        unsigned alo = u0.x, ahi = u0.y;                                       \
        _Pragma("unroll")                                                      \
        for (int k = 1; k < KK; ++k) {                                         \
            const int mk = __builtin_amdgcn_ds_bpermute(pb + (k << 2), mi);    \
            uint2 uk = *(const uint2*)&cfb[((size_t)mk << 6) + qc];            \
            alo = pkmax(alo, uk.x);                                            \
            ahi = pkmax(ahi, uk.y);                                            \
        }                                                                      \
        *(unsigned*)&ah[wv][(g << 2) + rr][qc]     = alo;                      \
        *(unsigned*)&ah[wv][(g << 2) + rr][qc + 2] = ahi;                      \
    } while (0)

    GATHER_G(mi0, 0);
    GATHER_G(mi1, 1);
    GATHER_G(mi2, 2);
    GATHER_G(mi3, 3);
#undef GATHER_G
    __builtin_amdgcn_wave_barrier();

    // A-fragments: row = lane&15, k = (lane>>4)*8 + j (+32 for the second)
    const half8 a0 = *(const half8*)&ah[wv][lane & 15][((lane >> 4) << 3)];
    const half8 a1 = *(const half8*)&ah[wv][lane & 15][32 + ((lane >> 4) << 3)];

    f32x4 ac0 = {0.f, 0.f, 0.f, 0.f}, ac1 = ac0, ac2 = ac0, ac3 = ac0;
    ac0 = MFMA16(a0, b00, ac0); ac0 = MFMA16(a1, b01, ac0);
    ac1 = MFMA16(a0, b10, ac1); ac1 = MFMA16(a1, b11, ac1);
    ac2 = MFMA16(a0, b20, ac2); ac2 = MFMA16(a1, b21, ac2);
    ac3 = MFMA16(a0, b30, ac3); ac3 = MFMA16(a1, b31, ac3);
    __builtin_amdgcn_wave_barrier();

    // epilogue: y = acc + bias; raw y out; stats. C layout: col=lane&15, row=(lane>>4)*4+j
    float ps0 = 0.f, ps1 = 0.f, ps2 = 0.f, ps3 = 0.f;
    float pq0 = 0.f, pq1 = 0.f, pq2 = 0.f, pq3 = 0.f;
    const int rl = rbase + ((lane >> 4) << 2);
    const int cl = lane & 15;
#pragma unroll
    for (int j = 0; j < 4; ++j) {
        const size_t ob = (size_t)(rl + j) * OUTW + 3 + cl;
        const float y0 = ac0[j] + bias0;
        const float y1 = ac1[j] + bias1;
        const float y2 = ac2[j] + bias2;
        const float y3 = ac3[j] + bias3;
        out[ob +  0] = y0;
        out[ob + 16] = y1;
        out[ob + 32] = y2;
        out[ob + 48] = y3;
        ps0 += y0; pq0 += y0 * y0;
        ps1 += y1; pq1 += y1 * y1;
        ps2 += y2; pq2 += y2 * y2;
        ps3 += y3; pq3 += y3 * y3;
    }

    atomicAdd(&lsum[cl +  0], ps0); atomicAdd(&lsq[cl +  0], pq0);
    atomicAdd(&lsum[cl + 16], ps1); atomicAdd(&lsq[cl + 16], pq1);
    atomicAdd(&lsum[cl + 32], ps2); atomicAdd(&lsq[cl + 32], pq2);
    atomicAdd(&lsum[cl + 48], ps3); atomicAdd(&lsq[cl + 48], pq3);
    __syncthreads();
    if (threadIdx.x < 64) {
        atomicAdd(&acc[threadIdx.x],      lsum[threadIdx.x]);
        atomicAdd(&acc[64 + threadIdx.x], lsq[threadIdx.x]);
    }
}

// ---------------------------------------------------------------------------
// Kernel 1 (fallback, r7-identical f32 gather) — used only if ws is too small
// ---------------------------------------------------------------------------
__device__ __forceinline__ h2 gpair(const float* __restrict__ cfb, int mi, int pb, int coff) {
    float q0x = -3.402823466e38f, q0y = q0x, q1x = q0x, q1y = q0x;
#pragma unroll
    for (int k = 0; k < KK; k += 2) {
        const int m0 = __builtin_amdgcn_ds_bpermute(pb + (k << 2), mi);
        const int m1 = __builtin_amdgcn_ds_bpermute(pb + ((k + 1) << 2), mi);
        const float2 v0 = *(const float2*)&cfb[((size_t)m0 << 6) + coff];
        const float2 v1 = *(const float2*)&cfb[((size_t)m1 << 6) + coff];
        q0x = fmaxf(q0x, v0.x); q0y = fmaxf(q0y, v0.y);
        q1x = fmaxf(q1x, v1.x); q1y = fmaxf(q1y, v1.y);
    }
    h2 h;
    h[0] = (_Float16)fmaxf(q0x, q1x);
    h[1] = (_Float16)fmaxf(q0y, q1y);
    return h;
}

__global__ __launch_bounds__(256) void k_pool_proj_f32(
    const float* __restrict__ cf, const int* __restrict__ idxs,
    const float* __restrict__ scoord,
    const float* __restrict__ W1, const float* __restrict__ b1,
    float* __restrict__ out, float* __restrict__ acc)
{
    __shared__ _Float16 ah[4][TROWS][APAD];
    __shared__ float lsum[64], lsq[64];
    const int lane = threadIdx.x & 63;
    const int wv   = threadIdx.x >> 6;
    if (threadIdx.x < 64) { lsum[threadIdx.x] = 0.f; lsq[threadIdx.x] = 0.f; }
    __syncthreads();

    const int w     = blockIdx.x;
    const int xcd   = w & 7;
    const int batch = xcd >> 1;
    const int lb    = (w >> 3) + ((xcd & 1) << 8);
    const int rbase = batch * NN + (lb * 4 + wv) * TROWS;
    const float* cfb = cf + ((size_t)batch << 20);

    const half8 b00 = load_bfrag(W1, lane, 0, 0), b01 = load_bfrag(W1, lane, 0, 1);
    const half8 b10 = load_bfrag(W1, lane, 1, 0), b11 = load_bfrag(W1, lane, 1, 1);
    const half8 b20 = load_bfrag(W1, lane, 2, 0), b21 = load_bfrag(W1, lane, 2, 1);
    const half8 b30 = load_bfrag(W1, lane, 3, 0), b31 = load_bfrag(W1, lane, 3, 1);
    const float bias0 = b1[(lane & 15) +  0], bias1 = b1[(lane & 15) + 16];
    const float bias2 = b1[(lane & 15) + 32], bias3 = b1[(lane & 15) + 48];

    const int mi0 = idxs[(size_t)(rbase +  0) * KK + lane];
    const int mi1 = idxs[(size_t)(rbase +  4) * KK + lane];
    const int mi2 = idxs[(size_t)(rbase +  8) * KK + lane];
    const int mi3 = idxs[(size_t)(rbase + 12) * KK + lane];

    if (lane < 48) {
        const float cv = scoord[(size_t)rbase * 3 + lane];
        const int rj = lane / 3;
        out[(size_t)(rbase + rj) * OUTW + (lane - rj * 3)] = cv;
    }

    const int rr   = lane >> 5;
    const int coff = (lane & 31) << 1;
    const int pb0  = (0 + rr) << 6;
    const int pb2  = (2 + rr) << 6;

    *(h2*)&ah[wv][ 0 + rr][coff] = gpair(cfb, mi0, pb0, coff);
    *(h2*)&ah[wv][ 2 + rr][coff] = gpair(cfb, mi0, pb2, coff);
    *(h2*)&ah[wv][ 4 + rr][coff] = gpair(cfb, mi1, pb0, coff);
    *(h2*)&ah[wv][ 6 + rr][coff] = gpair(cfb, mi1, pb2, coff);
    *(h2*)&ah[wv][ 8 + rr][coff] = gpair(cfb, mi2, pb0, coff);
    *(h2*)&ah[wv][10 + rr][coff] = gpair(cfb, mi2, pb2, coff);
    *(h2*)&ah[wv][12 + rr][coff] = gpair(cfb, mi3, pb0, coff);
    *(h2*)&ah[wv][14 + rr][coff] = gpair(cfb, mi3, pb2, coff);
    __builtin_amdgcn_wave_barrier();

    const half8 a0 = *(const half8*)&ah[wv][lane & 15][((lane >> 4) << 3)];
    const half8 a1 = *(const half8*)&ah[wv][lane & 15][32 + ((lane >> 4) << 3)];

    f32x4 ac0 = {0.f, 0.f, 0.f, 0.f}, ac1 = ac0, ac2 = ac0, ac3 = ac0;
    ac0 = MFMA16(a0, b00, ac0); ac0 = MFMA16(a1, b01, ac0);
    ac1 = MFMA16(a0, b10, ac1); ac1 = MFMA16(a1, b11, ac1);
    ac2 = MFMA16(a0, b20, ac2); ac2 = MFMA16(a1, b21, ac2);
    ac3 = MFMA16(a0, b30, ac3); ac3 = MFMA16(a1, b31, ac3);
    __builtin_amdgcn_wave_barrier();

    float ps0 = 0.f, ps1 = 0.f, ps2 = 0.f, ps3 = 0.f;
    float pq0 = 0.f, pq1 = 0.f, pq2 = 0.f, pq3 = 0.f;
    const int rl = rbase + ((lane >> 4) << 2);
    const int cl = lane & 15;
#pragma unroll
    for (int j = 0; j < 4; ++j) {
        const size_t ob = (size_t)(rl + j) * OUTW + 3 + cl;
        const float y0 = ac0[j] + bias0;
        const float y1 = ac1[j] + bias1;
        const float y2 = ac2[j] + bias2;
        const float y3 = ac3[j] + bias3;
        out[ob +  0] = y0;
        out[ob + 16] = y1;
        out[ob + 32] = y2;
        out[ob + 48] = y3;
        ps0 += y0; pq0 += y0 * y0;
        ps1 += y1; pq1 += y1 * y1;
        ps2 += y2; pq2 += y2 * y2;
        ps3 += y3; pq3 += y3 * y3;
    }

    atomicAdd(&lsum[cl +  0], ps0); atomicAdd(&lsq[cl +  0], pq0);
    atomicAdd(&lsum[cl + 16], ps1); atomicAdd(&lsq[cl + 16], pq1);
    atomicAdd(&lsum[cl + 32], ps2); atomicAdd(&lsq[cl + 32], pq2);
    atomicAdd(&lsum[cl + 48], ps3); atomicAdd(&lsq[cl + 48], pq3);
    __syncthreads();
    if (threadIdx.x < 64) {
        atomicAdd(&acc[threadIdx.x],      lsum[threadIdx.x]);
        atomicAdd(&acc[64 + threadIdx.x], lsq[threadIdx.x]);
    }
}

// ---------------------------------------------------------------------------
// Kernel 2: (skip_feat @ W2 + b2) via MFMA -> out[..., 67:131]  (r7-identical)
// ---------------------------------------------------------------------------
__global__ __launch_bounds__(256) void k_skip_proj(
    const float* __restrict__ sf,
    const float* __restrict__ W2, const float* __restrict__ b2,
    float* __restrict__ out, float* __restrict__ acc)
{
    __shared__ float lsum[64], lsq[64];
    const int lane = threadIdx.x & 63;
    const int wv   = threadIdx.x >> 6;
    if (threadIdx.x < 64) { lsum[threadIdx.x] = 0.f; lsq[threadIdx.x] = 0.f; }
    __syncthreads();

    const int tb = (blockIdx.x * 4 + wv) * TROWS;

    const half8 b00 = load_bfrag(W2, lane, 0, 0), b01 = load_bfrag(W2, lane, 0, 1);
    const half8 b10 = load_bfrag(W2, lane, 1, 0), b11 = load_bfrag(W2, lane, 1, 1);
    const half8 b20 = load_bfrag(W2, lane, 2, 0), b21 = load_bfrag(W2, lane, 2, 1);
    const half8 b30 = load_bfrag(W2, lane, 3, 0), b31 = load_bfrag(W2, lane, 3, 1);
    const float bias0 = b2[(lane & 15) +  0], bias1 = b2[(lane & 15) + 16];
    const float bias2 = b2[(lane & 15) + 32], bias3 = b2[(lane & 15) + 48];

    const size_t ab = (size_t)(tb + (lane & 15)) * 64 + ((lane >> 4) << 3);
    const float4 f0 = *(const float4*)&sf[ab +  0];
    const float4 f1 = *(const float4*)&sf[ab +  4];
    const float4 f2 = *(const float4*)&sf[ab + 32];
    const float4 f3 = *(const float4*)&sf[ab + 36];
    const half8 a0 = {(_Float16)f0.x, (_Float16)f0.y, (_Float16)f0.z, (_Float16)f0.w,
                      (_Float16)f1.x, (_Float16)f1.y, (_Float16)f1.z, (_Float16)f1.w};
    const half8 a1 = {(_Float16)f2.x, (_Float16)f2.y, (_Float16)f2.z, (_Float16)f2.w,
                      (_Float16)f3.x, (_Float16)f3.y, (_Float16)f3.z, (_Float16)f3.w};

    f32x4 ac0 = {0.f, 0.f, 0.f, 0.f}, ac1 = ac0, ac2 = ac0, ac3 = ac0;
    ac0 = MFMA16(a0, b00, ac0); ac0 = MFMA16(a1, b01, ac0);
    ac1 = MFMA16(a0, b10, ac1); ac1 = MFMA16(a1, b11, ac1);
    ac2 = MFMA16(a0, b20, ac2); ac2 = MFMA16(a1, b21, ac2);
    ac3 = MFMA16(a0, b30, ac3); ac3 = MFMA16(a1, b31, ac3);

    float ps0 = 0.f, ps1 = 0.f, ps2 = 0.f, ps3 = 0.f;
    float pq0 = 0.f, pq1 = 0.f, pq2 = 0.f, pq3 = 0.f;
    const int rl = tb + ((lane >> 4) << 2);
    const int cl = lane & 15;
#pragma unroll
    for (int j = 0; j < 4; ++j) {
        const size_t ob = (size_t)(rl + j) * OUTW + 67 + cl;
        const float y0 = ac0[j] + bias0;
        const float y1 = ac1[j] + bias1;
        const float y2 = ac2[j] + bias2;
        const float y3 = ac3[j] + bias3;
        out[ob +  0] = y0;
        out[ob + 16] = y1;
        out[ob + 32] = y2;
        out[ob + 48] = y3;
        ps0 += y0; pq0 += y0 * y0;
        ps1 += y1; pq1 += y1 * y1;
        ps2 += y2; pq2 += y2 * y2;
        ps3 += y3; pq3 += y3 * y3;
    }

    atomicAdd(&lsum[cl +  0], ps0); atomicAdd(&lsq[cl +  0], pq0);
    atomicAdd(&lsum[cl + 16], ps1); atomicAdd(&lsq[cl + 16], pq1);
    atomicAdd(&lsum[cl + 32], ps2); atomicAdd(&lsq[cl + 32], pq2);
    atomicAdd(&lsum[cl + 48], ps3); atomicAdd(&lsq[cl + 48], pq3);
    __syncthreads();
    if (threadIdx.x < 64) {
        atomicAdd(&acc[128 + threadIdx.x], lsum[threadIdx.x]);
        atomicAdd(&acc[192 + threadIdx.x], lsq[threadIdx.x]);
    }
}

// ---------------------------------------------------------------------------
// Kernel 3: fold sums -> affine params  a = g*rsqrt(var+eps), c = beta - mu*a
// ---------------------------------------------------------------------------
__global__ void k_stats(float* __restrict__ ws,
                        const float* __restrict__ g1, const float* __restrict__ be1,
                        const float* __restrict__ g2, const float* __restrict__ be2)
{
    const int o = threadIdx.x;  // 64 threads
    const float inv = 1.0f / (float)ROWS;
    float m1 = ws[o] * inv;
    float v1 = ws[64 + o] * inv - m1 * m1;
    float a1 = g1[o] * rsqrtf(v1 + 1e-5f);
    ws[256 + o] = a1;
    ws[384 + o] = be1[o] - m1 * a1;
    float m2 = ws[128 + o] * inv;
    float v2 = ws[192 + o] * inv - m2 * m2;
    float a2 = g2[o] * rsqrtf(v2 + 1e-5f);
    ws[256 + 64 + o] = a2;
    ws[384 + 64 + o] = be2[o] - m2 * a2;
}

// ---------------------------------------------------------------------------
// Kernel 4: in-place  out[r*131 + 3 + j] = relu(a[j]*y + c[j]),  j in [0,128)
// ---------------------------------------------------------------------------
__global__ __launch_bounds__(256) void k_finalize(float* __restrict__ out,
                                                  const float* __restrict__ ws)
{
    const size_t T  = (size_t)gridDim.x * blockDim.x;
    const size_t t0 = (size_t)blockIdx.x * blockDim.x + threadIdx.x;
#pragma unroll
    for (int i = 0; i < 4; ++i) {
        const size_t e = t0 + (size_t)i * T;       // e < ROWS*128
        const size_t r = e >> 7;
        const int    j = (int)(e & 127);
        const size_t ad = r * OUTW + 3 + j;
        const float v = out[ad];
        out[ad] = fmaxf(fmaf(v, ws[256 + j], ws[384 + j]), 0.f);
    }
}

// ---------------------------------------------------------------------------
extern "C" void kernel_launch(void* const* d_in, const int* in_sizes, int n_in,
                              void* d_out, int out_size, void* d_ws, size_t ws_size,
                              hipStream_t stream)
{
    const float* cf     = (const float*)d_in[1];   // curr_feat (B,M,64)
    const float* scoord = (const float*)d_in[2];   // skip_coords (B,N,3)
    const float* sf     = (const float*)d_in[3];   // skip_feat (B,N,64)
    const int*   idxs   = (const int*)  d_in[4];   // upsampling_idxs (B,N,16)
    const float* W1     = (const float*)d_in[5];
    const float* b1     = (const float*)d_in[6];
    const float* g1     = (const float*)d_in[7];
    const float* be1    = (const float*)d_in[8];
    const float* W2     = (const float*)d_in[9];
    const float* b2     = (const float*)d_in[10];
    const float* g2     = (const float*)d_in[11];
    const float* be2    = (const float*)d_in[12];
    float* out = (float*)d_out;
    float* ws  = (float*)d_ws;

    (void)hipMemsetAsync(ws, 0, 2048, stream);  // zero the stat accumulators

    if (ws_size >= 2048 + CFH_BYTES) {
        _Float16* cfh = (_Float16*)((char*)ws + 2048);
        // 4,194,304 f32 -> f16 : 4096 blocks x 256 threads x 1 float4
        k_half<<<4096, 256, 0, stream>>>(cf, cfh);
        k_pool_proj_h<<<A_BLOCKS, 256, 0, stream>>>(cfh, idxs, scoord, W1, b1, out, ws);
    } else {
        k_pool_proj_f32<<<A_BLOCKS, 256, 0, stream>>>(cf, idxs, scoord, W1, b1, out, ws);
    }
    k_skip_proj<<<A_BLOCKS, 256, 0, stream>>>(sf, W2, b2, out, ws);
    k_stats<<<1, 64, 0, stream>>>(ws, g1, be1, g2, be2);
    k_finalize<<<16384, 256, 0, stream>>>(out, ws);
}

// Round 12
// 245.078 us; speedup vs baseline: 1.2970x; 1.1230x over previous
//
#include <hip/hip_runtime.h>

// Problem constants (from reference setup_inputs)
#define BB 4
#define MM 16384
#define NN 32768
#define KK 16
#define ROWS (BB * NN)   // 131072
#define OUTW 131         // 3 coords + 64 + 64
#define TROWS 16         // rows per MFMA tile
#define POOL_BLOCKS 2048 // pool part: 4 waves x 1 tile = 64 rows/block
#define SKIP_BLOCKS 512  // skip part: 4 waves x 4 tiles = 256 rows/block
#define PROJ_BLOCKS (POOL_BLOCKS + SKIP_BLOCKS)   // 2560
#define APAD 72          // padded k-stride of LDS A-tile in f16 units
#define FIN_BLOCKS 2096  // 2096*256*8 float4 == 131072*131/4 exactly

// Lessons encoded:
//  r1-r3: NO runtime-indexed per-thread arrays; named scalars/ext-vectors only.
//  r1/r4: XCD swizzle validated (FETCH 211->67MB).
//  r4/r5/r7: MFMA projections validated (pool 93us, f32 gather).
//  r9:    f16-copy gather: pool 83us but +1 dispatch (~wash); dropped here.
//  r10/r11: grid-barrier kernel killed the container twice (r11 had no OOB);
//         barrier ABANDONED. Accounting shows ~115us of the 275 is dispatch
//         overhead (~20us x 6) -> THIS ROUND: 6 dispatches -> 4.
//         (a) skip-proj merged into the pool dispatch (independent blocks),
//         (b) stats-fold merged into finalize (redundant per-block fold),
//         (c) finalize = aligned linear float4 sweep over all 131 columns.

typedef _Float16 half8 __attribute__((ext_vector_type(8)));
typedef _Float16 h2    __attribute__((ext_vector_type(2)));
typedef float f32x4 __attribute__((ext_vector_type(4)));

#define MFMA16(a, b, c) __builtin_amdgcn_mfma_f32_16x16x32_f16(a, b, c, 0, 0, 0)

// B-fragment (32x16 of W, f16): lane holds k = kt*32 + (lane>>4)*8 + j, col = ot*16 + (lane&15)
__device__ __forceinline__ half8 load_bfrag(const float* __restrict__ W, int lane, int ot, int kt) {
    const int kb  = kt * 32 + ((lane >> 4) << 3);
    const int col = ot * 16 + (lane & 15);
    half8 b;
#pragma unroll
    for (int j = 0; j < 8; ++j) b[j] = (_Float16)W[(kb + j) * 64 + col];
    return b;
}

// Gather+max one ROW-PAIR (r7-validated): lanes<32 own row sub, lanes>=32 row sub+1.
__device__ __forceinline__ h2 gpair(const float* __restrict__ cfb, int mi, int pb, int coff) {
    float q0x = -3.402823466e38f, q0y = q0x, q1x = q0x, q1y = q0x;
#pragma unroll
    for (int k = 0; k < KK; k += 2) {
        const int m0 = __builtin_amdgcn_ds_bpermute(pb + (k << 2), mi);
        const int m1 = __builtin_amdgcn_ds_bpermute(pb + ((k + 1) << 2), mi);
        const float2 v0 = *(const float2*)&cfb[((size_t)m0 << 6) + coff];
        const float2 v1 = *(const float2*)&cfb[((size_t)m1 << 6) + coff];
        q0x = fmaxf(q0x, v0.x); q0y = fmaxf(q0y, v0.y);
        q1x = fmaxf(q1x, v1.x); q1y = fmaxf(q1y, v1.y);
    }
    h2 h;
    h[0] = (_Float16)fmaxf(q0x, q1x);
    h[1] = (_Float16)fmaxf(q0y, q1y);
    return h;
}

// ---------------------------------------------------------------------------
// Kernel 1: combined projection dispatch.
//   blocks [0, 2048): gather + max-pool + proj1 (r7-validated body)
//       raw y1 -> out[..., 3:67], coords -> out[..., 0:3], stats -> ws[0:128]
//   blocks [2048, 2560): skip proj, 4 tiles/wave
//       raw y2 -> out[..., 67:131], stats -> ws[128:256]
// Independent work; skip blocks backfill CUs as pool blocks retire.
// ---------------------------------------------------------------------------
__global__ __launch_bounds__(256) void k_proj(
    const float* __restrict__ cf, const int* __restrict__ idxs,
    const float* __restrict__ scoord, const float* __restrict__ sf,
    const float* __restrict__ W1, const float* __restrict__ b1,
    const float* __restrict__ W2, const float* __restrict__ b2,
    float* __restrict__ out, float* __restrict__ ws)
{
    __shared__ _Float16 ah[4][TROWS][APAD];
    __shared__ float lsum[64], lsq[64];
    const int lane = threadIdx.x & 63;
    const int wv   = threadIdx.x >> 6;
    const int cl   = lane & 15;
    if (threadIdx.x < 64) { lsum[threadIdx.x] = 0.f; lsq[threadIdx.x] = 0.f; }
    __syncthreads();

    if (blockIdx.x < POOL_BLOCKS) {
        // ================= POOL + PROJ1 (r7-validated) =================
        // XCD swizzle: block w -> XCD w&7; each batch owns 2 XCDs so its
        // 4.2 MB cf slice stays L2-resident.
        const int w     = blockIdx.x;
        const int xcd   = w & 7;
        const int batch = xcd >> 1;
        const int lb    = (w >> 3) + ((xcd & 1) << 8);   // [0,512) per batch
        const int rbase = batch * NN + (lb * 4 + wv) * TROWS;
        const float* cfb = cf + ((size_t)batch << 20);

        const half8 b00 = load_bfrag(W1, lane, 0, 0), b01 = load_bfrag(W1, lane, 0, 1);
        const half8 b10 = load_bfrag(W1, lane, 1, 0), b11 = load_bfrag(W1, lane, 1, 1);
        const half8 b20 = load_bfrag(W1, lane, 2, 0), b21 = load_bfrag(W1, lane, 2, 1);
        const half8 b30 = load_bfrag(W1, lane, 3, 0), b31 = load_bfrag(W1, lane, 3, 1);
        const float bias0 = b1[cl +  0], bias1 = b1[cl + 16];
        const float bias2 = b1[cl + 32], bias3 = b1[cl + 48];

        const int mi0 = idxs[(size_t)(rbase +  0) * KK + lane];
        const int mi1 = idxs[(size_t)(rbase +  4) * KK + lane];
        const int mi2 = idxs[(size_t)(rbase +  8) * KK + lane];
        const int mi3 = idxs[(size_t)(rbase + 12) * KK + lane];

        if (lane < 48) {
            const float cv = scoord[(size_t)rbase * 3 + lane];
            const int rj = lane / 3;
            out[(size_t)(rbase + rj) * OUTW + (lane - rj * 3)] = cv;
        }

        const int rr   = lane >> 5;
        const int coff = (lane & 31) << 1;
        const int pb0  = (0 + rr) << 6;
        const int pb2  = (2 + rr) << 6;

        *(h2*)&ah[wv][ 0 + rr][coff] = gpair(cfb, mi0, pb0, coff);
        *(h2*)&ah[wv][ 2 + rr][coff] = gpair(cfb, mi0, pb2, coff);
        *(h2*)&ah[wv][ 4 + rr][coff] = gpair(cfb, mi1, pb0, coff);
        *(h2*)&ah[wv][ 6 + rr][coff] = gpair(cfb, mi1, pb2, coff);
        *(h2*)&ah[wv][ 8 + rr][coff] = gpair(cfb, mi2, pb0, coff);
        *(h2*)&ah[wv][10 + rr][coff] = gpair(cfb, mi2, pb2, coff);
        *(h2*)&ah[wv][12 + rr][coff] = gpair(cfb, mi3, pb0, coff);
        *(h2*)&ah[wv][14 + rr][coff] = gpair(cfb, mi3, pb2, coff);
        __builtin_amdgcn_wave_barrier();

        const half8 a0 = *(const half8*)&ah[wv][cl][((lane >> 4) << 3)];
        const half8 a1 = *(const half8*)&ah[wv][cl][32 + ((lane >> 4) << 3)];

        f32x4 ac0 = {0.f, 0.f, 0.f, 0.f}, ac1 = ac0, ac2 = ac0, ac3 = ac0;
        ac0 = MFMA16(a0, b00, ac0); ac0 = MFMA16(a1, b01, ac0);
        ac1 = MFMA16(a0, b10, ac1); ac1 = MFMA16(a1, b11, ac1);
        ac2 = MFMA16(a0, b20, ac2); ac2 = MFMA16(a1, b21, ac2);
        ac3 = MFMA16(a0, b30, ac3); ac3 = MFMA16(a1, b31, ac3);
        __builtin_amdgcn_wave_barrier();

        float ps0 = 0.f, ps1 = 0.f, ps2 = 0.f, ps3 = 0.f;
        float pq0 = 0.f, pq1 = 0.f, pq2 = 0.f, pq3 = 0.f;
        const int rl = rbase + ((lane >> 4) << 2);
#pragma unroll
        for (int j = 0; j < 4; ++j) {
            const size_t ob = (size_t)(rl + j) * OUTW + 3 + cl;
            const float y0 = ac0[j] + bias0;
            const float y1 = ac1[j] + bias1;
            const float y2 = ac2[j] + bias2;
            const float y3 = ac3[j] + bias3;
            out[ob +  0] = y0;
            out[ob + 16] = y1;
            out[ob + 32] = y2;
            out[ob + 48] = y3;
            ps0 += y0; pq0 += y0 * y0;
            ps1 += y1; pq1 += y1 * y1;
            ps2 += y2; pq2 += y2 * y2;
            ps3 += y3; pq3 += y3 * y3;
        }

        atomicAdd(&lsum[cl +  0], ps0); atomicAdd(&lsq[cl +  0], pq0);
        atomicAdd(&lsum[cl + 16], ps1); atomicAdd(&lsq[cl + 16], pq1);
        atomicAdd(&lsum[cl + 32], ps2); atomicAdd(&lsq[cl + 32], pq2);
        atomicAdd(&lsum[cl + 48], ps3); atomicAdd(&lsq[cl + 48], pq3);
        __syncthreads();
        if (threadIdx.x < 64) {
            atomicAdd(&ws[threadIdx.x],      lsum[threadIdx.x]);
            atomicAdd(&ws[64 + threadIdx.x], lsq[threadIdx.x]);
        }
    } else {
        // ================= SKIP PROJ2 (r7 body x 4 tiles/wave) =================
        const int sb = blockIdx.x - POOL_BLOCKS;   // [0, 512)
        const half8 b00 = load_bfrag(W2, lane, 0, 0), b01 = load_bfrag(W2, lane, 0, 1);
        const half8 b10 = load_bfrag(W2, lane, 1, 0), b11 = load_bfrag(W2, lane, 1, 1);
        const half8 b20 = load_bfrag(W2, lane, 2, 0), b21 = load_bfrag(W2, lane, 2, 1);
        const half8 b30 = load_bfrag(W2, lane, 3, 0), b31 = load_bfrag(W2, lane, 3, 1);
        const float bias0 = b2[cl +  0], bias1 = b2[cl + 16];
        const float bias2 = b2[cl + 32], bias3 = b2[cl + 48];

        float ps0 = 0.f, ps1 = 0.f, ps2 = 0.f, ps3 = 0.f;
        float pq0 = 0.f, pq1 = 0.f, pq2 = 0.f, pq3 = 0.f;

        for (int t = 0; t < 4; ++t) {                 // 4 tiles per wave
            const int tb = (((sb * 4 + wv) << 2) + t) * TROWS;
            const size_t ab = (size_t)(tb + cl) * 64 + ((lane >> 4) << 3);
            const float4 e0 = *(const float4*)&sf[ab +  0];
            const float4 e1 = *(const float4*)&sf[ab +  4];
            const float4 e2 = *(const float4*)&sf[ab + 32];
            const float4 e3 = *(const float4*)&sf[ab + 36];
            const half8 a0 = {(_Float16)e0.x, (_Float16)e0.y, (_Float16)e0.z, (_Float16)e0.w,
                              (_Float16)e1.x, (_Float16)e1.y, (_Float16)e1.z, (_Float16)e1.w};
            const half8 a1 = {(_Float16)e2.x, (_Float16)e2.y, (_Float16)e2.z, (_Float16)e2.w,
                              (_Float16)e3.x, (_Float16)e3.y, (_Float16)e3.z, (_Float16)e3.w};

            f32x4 ac0 = {0.f, 0.f, 0.f, 0.f}, ac1 = ac0, ac2 = ac0, ac3 = ac0;
            ac0 = MFMA16(a0, b00, ac0); ac0 = MFMA16(a1, b01, ac0);
            ac1 = MFMA16(a0, b10, ac1); ac1 = MFMA16(a1, b11, ac1);
            ac2 = MFMA16(a0, b20, ac2); ac2 = MFMA16(a1, b21, ac2);
            ac3 = MFMA16(a0, b30, ac3); ac3 = MFMA16(a1, b31, ac3);

            const int rl = tb + ((lane >> 4) << 2);
#pragma unroll
            for (int j = 0; j < 4; ++j) {
                const size_t ob = (size_t)(rl + j) * OUTW + 67 + cl;
                const float y0 = ac0[j] + bias0;
                const float y1 = ac1[j] + bias1;
                const float y2 = ac2[j] + bias2;
                const float y3 = ac3[j] + bias3;
                out[ob +  0] = y0;
                out[ob + 16] = y1;
                out[ob + 32] = y2;
                out[ob + 48] = y3;
                ps0 += y0; pq0 += y0 * y0;
                ps1 += y1; pq1 += y1 * y1;
                ps2 += y2; pq2 += y2 * y2;
                ps3 += y3; pq3 += y3 * y3;
            }
        }

        atomicAdd(&lsum[cl +  0], ps0); atomicAdd(&lsq[cl +  0], pq0);
        atomicAdd(&lsum[cl + 16], ps1); atomicAdd(&lsq[cl + 16], pq1);
        atomicAdd(&lsum[cl + 32], ps2); atomicAdd(&lsq[cl + 32], pq2);
        atomicAdd(&lsum[cl + 48], ps3); atomicAdd(&lsq[cl + 48], pq3);
        __syncthreads();
        if (threadIdx.x < 64) {
            atomicAdd(&ws[128 + threadIdx.x], lsum[threadIdx.x]);
            atomicAdd(&ws[192 + threadIdx.x], lsq[threadIdx.x]);
        }
    }
}

// ---------------------------------------------------------------------------
// Kernel 2: fused stats-fold + BN/ReLU apply.
// Each block redundantly folds a/c for all 128 output channels into LDS
// (threads 0..63, ~1us total), then sweeps the output LINEARLY as aligned
// float4: e = global float index, r = e/131, c = e%131; c<3 -> passthrough,
// else v = relu(v * af[c-3] + cf_[c-3]).  2096 blocks x 256 thr x 8 float4
// == 131072*131/4 exactly.
// ---------------------------------------------------------------------------
__global__ __launch_bounds__(256) void k_fin(
    float* __restrict__ out, const float* __restrict__ ws,
    const float* __restrict__ g1, const float* __restrict__ be1,
    const float* __restrict__ g2, const float* __restrict__ be2)
{
    __shared__ float af[128], cf_[128];
    const int tid = threadIdx.x;
    if (tid < 64) {
        const float inv = 1.0f / (float)ROWS;
        const float m1 = ws[tid] * inv;
        const float v1 = ws[64 + tid] * inv - m1 * m1;
        const float a1 = g1[tid] * rsqrtf(v1 + 1e-5f);
        af[tid]  = a1;
        cf_[tid] = be1[tid] - m1 * a1;
        const float m2 = ws[128 + tid] * inv;
        const float v2 = ws[192 + tid] * inv - m2 * m2;
        const float a2 = g2[tid] * rsqrtf(v2 + 1e-5f);
        af[64 + tid]  = a2;
        cf_[64 + tid] = be2[tid] - m2 * a2;
    }
    __syncthreads();

    float4* o4 = (float4*)out;
#pragma unroll
    for (int i = 0; i < 8; ++i) {
        const unsigned f4 = blockIdx.x * 2048u + (unsigned)i * 256u + tid;
        float4 v = o4[f4];
        const unsigned e0 = f4 * 4u;
        const unsigned r0 = e0 / 131u;
        int c = (int)(e0 - r0 * 131u);
        // element 0
        if (c >= 3) v.x = fmaxf(fmaf(v.x, af[c - 3], cf_[c - 3]), 0.f);
        if (++c == 131) c = 0;
        if (c >= 3) v.y = fmaxf(fmaf(v.y, af[c - 3], cf_[c - 3]), 0.f);
        if (++c == 131) c = 0;
        if (c >= 3) v.z = fmaxf(fmaf(v.z, af[c - 3], cf_[c - 3]), 0.f);
        if (++c == 131) c = 0;
        if (c >= 3) v.w = fmaxf(fmaf(v.w, af[c - 3], cf_[c - 3]), 0.f);
        o4[f4] = v;
    }
}

// ---------------------------------------------------------------------------
extern "C" void kernel_launch(void* const* d_in, const int* in_sizes, int n_in,
                              void* d_out, int out_size, void* d_ws, size_t ws_size,
                              hipStream_t stream)
{
    const float* cf     = (const float*)d_in[1];   // curr_feat (B,M,64)
    const float* scoord = (const float*)d_in[2];   // skip_coords (B,N,3)
    const float* sf     = (const float*)d_in[3];   // skip_feat (B,N,64)
    const int*   idxs   = (const int*)  d_in[4];   // upsampling_idxs (B,N,16)
    const float* W1     = (const float*)d_in[5];
    const float* b1     = (const float*)d_in[6];
    const float* g1     = (const float*)d_in[7];
    const float* be1    = (const float*)d_in[8];
    const float* W2     = (const float*)d_in[9];
    const float* b2     = (const float*)d_in[10];
    const float* g2     = (const float*)d_in[11];
    const float* be2    = (const float*)d_in[12];
    float* out = (float*)d_out;
    float* ws  = (float*)d_ws;

    (void)hipMemsetAsync(ws, 0, 1024, stream);  // zero the 256 stat floats
    k_proj<<<PROJ_BLOCKS, 256, 0, stream>>>(cf, idxs, scoord, sf,
                                            W1, b1, W2, b2, out, ws);
    k_fin<<<FIN_BLOCKS, 256, 0, stream>>>(out, ws, g1, be1, g2, be2);
}

// Round 14
// 239.021 us; speedup vs baseline: 1.3298x; 1.0253x over previous
//
#include <hip/hip_runtime.h>

// Problem constants (from reference setup_inputs)
#define BB 4
#define MM 16384
#define NN 32768
#define KK 16
#define ROWS (BB * NN)   // 131072
#define OUTW 131         // 3 coords + 64 + 64
#define TROWS 16         // rows per MFMA tile
#define PROJ_BLOCKS 2560 // 2048 pool + 512 skip, INTERLEAVED (every 5th = skip)
#define APAD 72          // padded k-stride of LDS A-tile in f16 units
#define FIN_BLOCKS 2096  // 2096*256*8 float4 == 131072*131/4 exactly

// Lessons encoded:
//  r1-r3: NO runtime-indexed per-thread arrays; named scalars/ext-vectors only.
//  r1/r4: XCD swizzle validated (FETCH 211->67MB).
//  r4/r5/r7: MFMA projections validated.
//  r10/r11: grid barrier killed container twice -> abandoned.
//  r12:   merged dispatch = 245us; k_proj = 93 (pool) + 23 (skip TAIL).
//  r13:   interleaved roles; compile fail: __builtin_nontemporal_* rejects
//         HIP float4 (class type). THIS ROUND: same kernel, k_fin uses
//         clang ext_vector f32x4 (native vector) for the NT builtins.

typedef _Float16 half8 __attribute__((ext_vector_type(8)));
typedef _Float16 h2    __attribute__((ext_vector_type(2)));
typedef float f32x4 __attribute__((ext_vector_type(4)));

#define MFMA16(a, b, c) __builtin_amdgcn_mfma_f32_16x16x32_f16(a, b, c, 0, 0, 0)

// B-fragment (32x16 of W, f16): lane holds k = kt*32 + (lane>>4)*8 + j, col = ot*16 + (lane&15)
__device__ __forceinline__ half8 load_bfrag(const float* __restrict__ W, int lane, int ot, int kt) {
    const int kb  = kt * 32 + ((lane >> 4) << 3);
    const int col = ot * 16 + (lane & 15);
    half8 b;
#pragma unroll
    for (int j = 0; j < 8; ++j) b[j] = (_Float16)W[(kb + j) * 64 + col];
    return b;
}

// Gather+max one ROW-PAIR (r7-validated): lanes<32 own row sub, lanes>=32 row sub+1.
__device__ __forceinline__ h2 gpair(const float* __restrict__ cfb, int mi, int pb, int coff) {
    float q0x = -3.402823466e38f, q0y = q0x, q1x = q0x, q1y = q0x;
#pragma unroll
    for (int k = 0; k < KK; k += 2) {
        const int m0 = __builtin_amdgcn_ds_bpermute(pb + (k << 2), mi);
        const int m1 = __builtin_amdgcn_ds_bpermute(pb + ((k + 1) << 2), mi);
        const float2 v0 = *(const float2*)&cfb[((size_t)m0 << 6) + coff];
        const float2 v1 = *(const float2*)&cfb[((size_t)m1 << 6) + coff];
        q0x = fmaxf(q0x, v0.x); q0y = fmaxf(q0y, v0.y);
        q1x = fmaxf(q1x, v1.x); q1y = fmaxf(q1y, v1.y);
    }
    h2 h;
    h[0] = (_Float16)fmaxf(q0x, q1x);
    h[1] = (_Float16)fmaxf(q0y, q1y);
    return h;
}

// ---------------------------------------------------------------------------
// Kernel 1: combined projection dispatch, INTERLEAVED roles.
// Block b: XCD class x = b&7, slot t = b>>3 (0..319 per class).
// Within each class: t % 5 == t0(x) -> skip role (64 blocks), else pool (256).
// t0(x) = (18 - 2x) % 5 gives each class exactly 64 skips at uniform cadence,
// so all 8 XCDs run a 4:1 pool:skip mix from t=0.
//   pool: raw y1 -> out[3:67], coords -> out[0:3], stats -> ws[0:128]
//   skip: raw y2 -> out[67:131], stats -> ws[128:256]  (4 tiles/wave)
// ---------------------------------------------------------------------------
__global__ __launch_bounds__(256) void k_proj(
    const float* __restrict__ cf, const int* __restrict__ idxs,
    const float* __restrict__ scoord, const float* __restrict__ sf,
    const float* __restrict__ W1, const float* __restrict__ b1,
    const float* __restrict__ W2, const float* __restrict__ b2,
    float* __restrict__ out, float* __restrict__ ws)
{
    __shared__ _Float16 ah[4][TROWS][APAD];
    __shared__ float lsum[64], lsq[64];
    const int lane = threadIdx.x & 63;
    const int wv   = threadIdx.x >> 6;
    const int cl   = lane & 15;
    if (threadIdx.x < 64) { lsum[threadIdx.x] = 0.f; lsq[threadIdx.x] = 0.f; }
    __syncthreads();

    const int b  = blockIdx.x;        // 0..2559
    const int x  = b & 7;             // physical XCD class (round-robin)
    const int t  = b >> 3;            // 0..319 within class
    const int t0 = (18 - 2 * x) % 5;  // skip-phase for this class
    const bool is_skip = (t % 5) == t0;

    if (!is_skip) {
        // ================= POOL + PROJ1 (r7-validated body) =================
        const int ns = (t >= t0) ? ((t - t0) / 5 + 1) : 0;
        const int lp = t - ns;                    // [0,256) within class
        const int batch = x >> 1;                 // 2 XCD classes per batch
        const int lb = ((x & 1) << 8) + lp;       // [0,512) within batch
        const int rbase = batch * NN + (lb * 4 + wv) * TROWS;
        const float* cfb = cf + ((size_t)batch << 20);

        const half8 b00 = load_bfrag(W1, lane, 0, 0), b01 = load_bfrag(W1, lane, 0, 1);
        const half8 b10 = load_bfrag(W1, lane, 1, 0), b11 = load_bfrag(W1, lane, 1, 1);
        const half8 b20 = load_bfrag(W1, lane, 2, 0), b21 = load_bfrag(W1, lane, 2, 1);
        const half8 b30 = load_bfrag(W1, lane, 3, 0), b31 = load_bfrag(W1, lane, 3, 1);
        const float bias0 = b1[cl +  0], bias1 = b1[cl + 16];
        const float bias2 = b1[cl + 32], bias3 = b1[cl + 48];

        const int mi0 = idxs[(size_t)(rbase +  0) * KK + lane];
        const int mi1 = idxs[(size_t)(rbase +  4) * KK + lane];
        const int mi2 = idxs[(size_t)(rbase +  8) * KK + lane];
        const int mi3 = idxs[(size_t)(rbase + 12) * KK + lane];

        if (lane < 48) {
            const float cv = scoord[(size_t)rbase * 3 + lane];
            const int rj = lane / 3;
            out[(size_t)(rbase + rj) * OUTW + (lane - rj * 3)] = cv;
        }

        const int rr   = lane >> 5;
        const int coff = (lane & 31) << 1;
        const int pb0  = (0 + rr) << 6;
        const int pb2  = (2 + rr) << 6;

        *(h2*)&ah[wv][ 0 + rr][coff] = gpair(cfb, mi0, pb0, coff);
        *(h2*)&ah[wv][ 2 + rr][coff] = gpair(cfb, mi0, pb2, coff);
        *(h2*)&ah[wv][ 4 + rr][coff] = gpair(cfb, mi1, pb0, coff);
        *(h2*)&ah[wv][ 6 + rr][coff] = gpair(cfb, mi1, pb2, coff);
        *(h2*)&ah[wv][ 8 + rr][coff] = gpair(cfb, mi2, pb0, coff);
        *(h2*)&ah[wv][10 + rr][coff] = gpair(cfb, mi2, pb2, coff);
        *(h2*)&ah[wv][12 + rr][coff] = gpair(cfb, mi3, pb0, coff);
        *(h2*)&ah[wv][14 + rr][coff] = gpair(cfb, mi3, pb2, coff);
        __builtin_amdgcn_wave_barrier();

        const half8 a0 = *(const half8*)&ah[wv][cl][((lane >> 4) << 3)];
        const half8 a1 = *(const half8*)&ah[wv][cl][32 + ((lane >> 4) << 3)];

        f32x4 ac0 = {0.f, 0.f, 0.f, 0.f}, ac1 = ac0, ac2 = ac0, ac3 = ac0;
        ac0 = MFMA16(a0, b00, ac0); ac0 = MFMA16(a1, b01, ac0);
        ac1 = MFMA16(a0, b10, ac1); ac1 = MFMA16(a1, b11, ac1);
        ac2 = MFMA16(a0, b20, ac2); ac2 = MFMA16(a1, b21, ac2);
        ac3 = MFMA16(a0, b30, ac3); ac3 = MFMA16(a1, b31, ac3);
        __builtin_amdgcn_wave_barrier();

        float ps0 = 0.f, ps1 = 0.f, ps2 = 0.f, ps3 = 0.f;
        float pq0 = 0.f, pq1 = 0.f, pq2 = 0.f, pq3 = 0.f;
        const int rl = rbase + ((lane >> 4) << 2);
#pragma unroll
        for (int j = 0; j < 4; ++j) {
            const size_t ob = (size_t)(rl + j) * OUTW + 3 + cl;
            const float y0 = ac0[j] + bias0;
            const float y1 = ac1[j] + bias1;
            const float y2 = ac2[j] + bias2;
            const float y3 = ac3[j] + bias3;
            out[ob +  0] = y0;
            out[ob + 16] = y1;
            out[ob + 32] = y2;
            out[ob + 48] = y3;
            ps0 += y0; pq0 += y0 * y0;
            ps1 += y1; pq1 += y1 * y1;
            ps2 += y2; pq2 += y2 * y2;
            ps3 += y3; pq3 += y3 * y3;
        }

        atomicAdd(&lsum[cl +  0], ps0); atomicAdd(&lsq[cl +  0], pq0);
        atomicAdd(&lsum[cl + 16], ps1); atomicAdd(&lsq[cl + 16], pq1);
        atomicAdd(&lsum[cl + 32], ps2); atomicAdd(&lsq[cl + 32], pq2);
        atomicAdd(&lsum[cl + 48], ps3); atomicAdd(&lsq[cl + 48], pq3);
        __syncthreads();
        if (threadIdx.x < 64) {
            atomicAdd(&ws[threadIdx.x],      lsum[threadIdx.x]);
            atomicAdd(&ws[64 + threadIdx.x], lsq[threadIdx.x]);
        }
    } else {
        // ================= SKIP PROJ2 (r12 body, 4 tiles/wave) =================
        const int sb = x * 64 + (t - t0) / 5;     // [0,512) bijective
        const half8 b00 = load_bfrag(W2, lane, 0, 0), b01 = load_bfrag(W2, lane, 0, 1);
        const half8 b10 = load_bfrag(W2, lane, 1, 0), b11 = load_bfrag(W2, lane, 1, 1);
        const half8 b20 = load_bfrag(W2, lane, 2, 0), b21 = load_bfrag(W2, lane, 2, 1);
        const half8 b30 = load_bfrag(W2, lane, 3, 0), b31 = load_bfrag(W2, lane, 3, 1);
        const float bias0 = b2[cl +  0], bias1 = b2[cl + 16];
        const float bias2 = b2[cl + 32], bias3 = b2[cl + 48];

        float ps0 = 0.f, ps1 = 0.f, ps2 = 0.f, ps3 = 0.f;
        float pq0 = 0.f, pq1 = 0.f, pq2 = 0.f, pq3 = 0.f;

        for (int tt = 0; tt < 4; ++tt) {          // 4 tiles per wave
            const int tb = (((sb * 4 + wv) << 2) + tt) * TROWS;
            const size_t ab = (size_t)(tb + cl) * 64 + ((lane >> 4) << 3);
            const float4 e0 = *(const float4*)&sf[ab +  0];
            const float4 e1 = *(const float4*)&sf[ab +  4];
            const float4 e2 = *(const float4*)&sf[ab + 32];
            const float4 e3 = *(const float4*)&sf[ab + 36];
            const half8 a0 = {(_Float16)e0.x, (_Float16)e0.y, (_Float16)e0.z, (_Float16)e0.w,
                              (_Float16)e1.x, (_Float16)e1.y, (_Float16)e1.z, (_Float16)e1.w};
            const half8 a1 = {(_Float16)e2.x, (_Float16)e2.y, (_Float16)e2.z, (_Float16)e2.w,
                              (_Float16)e3.x, (_Float16)e3.y, (_Float16)e3.z, (_Float16)e3.w};

            f32x4 ac0 = {0.f, 0.f, 0.f, 0.f}, ac1 = ac0, ac2 = ac0, ac3 = ac0;
            ac0 = MFMA16(a0, b00, ac0); ac0 = MFMA16(a1, b01, ac0);
            ac1 = MFMA16(a0, b10, ac1); ac1 = MFMA16(a1, b11, ac1);
            ac2 = MFMA16(a0, b20, ac2); ac2 = MFMA16(a1, b21, ac2);
            ac3 = MFMA16(a0, b30, ac3); ac3 = MFMA16(a1, b31, ac3);

            const int rl = tb + ((lane >> 4) << 2);
#pragma unroll
            for (int j = 0; j < 4; ++j) {
                const size_t ob = (size_t)(rl + j) * OUTW + 67 + cl;
                const float y0 = ac0[j] + bias0;
                const float y1 = ac1[j] + bias1;
                const float y2 = ac2[j] + bias2;
                const float y3 = ac3[j] + bias3;
                out[ob +  0] = y0;
                out[ob + 16] = y1;
                out[ob + 32] = y2;
                out[ob + 48] = y3;
                ps0 += y0; pq0 += y0 * y0;
                ps1 += y1; pq1 += y1 * y1;
                ps2 += y2; pq2 += y2 * y2;
                ps3 += y3; pq3 += y3 * y3;
            }
        }

        atomicAdd(&lsum[cl +  0], ps0); atomicAdd(&lsq[cl +  0], pq0);
        atomicAdd(&lsum[cl + 16], ps1); atomicAdd(&lsq[cl + 16], pq1);
        atomicAdd(&lsum[cl + 32], ps2); atomicAdd(&lsq[cl + 32], pq2);
        atomicAdd(&lsum[cl + 48], ps3); atomicAdd(&lsq[cl + 48], pq3);
        __syncthreads();
        if (threadIdx.x < 64) {
            atomicAdd(&ws[128 + threadIdx.x], lsum[threadIdx.x]);
            atomicAdd(&ws[192 + threadIdx.x], lsq[threadIdx.x]);
        }
    }
}

// ---------------------------------------------------------------------------
// Kernel 2: fused stats-fold + BN/ReLU apply (r12-validated), with
// nontemporal load/store via clang ext_vector f32x4 (native vector type —
// HIP float4 is a class and the NT builtins reject it, r13 compile fail).
// ---------------------------------------------------------------------------
__global__ __launch_bounds__(256) void k_fin(
    float* __restrict__ out, const float* __restrict__ ws,
    const float* __restrict__ g1, const float* __restrict__ be1,
    const float* __restrict__ g2, const float* __restrict__ be2)
{
    __shared__ float af[128], cf_[128];
    const int tid = threadIdx.x;
    if (tid < 64) {
        const float inv = 1.0f / (float)ROWS;
        const float m1 = ws[tid] * inv;
        const float v1 = ws[64 + tid] * inv - m1 * m1;
        const float a1 = g1[tid] * rsqrtf(v1 + 1e-5f);
        af[tid]  = a1;
        cf_[tid] = be1[tid] - m1 * a1;
        const float m2 = ws[128 + tid] * inv;
        const float v2 = ws[192 + tid] * inv - m2 * m2;
        const float a2 = g2[tid] * rsqrtf(v2 + 1e-5f);
        af[64 + tid]  = a2;
        cf_[64 + tid] = be2[tid] - m2 * a2;
    }
    __syncthreads();

    f32x4* o4 = (f32x4*)out;
#pragma unroll
    for (int i = 0; i < 8; ++i) {
        const unsigned f4 = blockIdx.x * 2048u + (unsigned)i * 256u + tid;
        f32x4 v = __builtin_nontemporal_load(&o4[f4]);
        const unsigned e0 = f4 * 4u;
        const unsigned r0 = e0 / 131u;
        int c = (int)(e0 - r0 * 131u);
        if (c >= 3) v.x = fmaxf(fmaf(v.x, af[c - 3], cf_[c - 3]), 0.f);
        if (++c == 131) c = 0;
        if (c >= 3) v.y = fmaxf(fmaf(v.y, af[c - 3], cf_[c - 3]), 0.f);
        if (++c == 131) c = 0;
        if (c >= 3) v.z = fmaxf(fmaf(v.z, af[c - 3], cf_[c - 3]), 0.f);
        if (++c == 131) c = 0;
        if (c >= 3) v.w = fmaxf(fmaf(v.w, af[c - 3], cf_[c - 3]), 0.f);
        __builtin_nontemporal_store(v, &o4[f4]);
    }
}

// ---------------------------------------------------------------------------
extern "C" void kernel_launch(void* const* d_in, const int* in_sizes, int n_in,
                              void* d_out, int out_size, void* d_ws, size_t ws_size,
                              hipStream_t stream)
{
    const float* cf     = (const float*)d_in[1];   // curr_feat (B,M,64)
    const float* scoord = (const float*)d_in[2];   // skip_coords (B,N,3)
    const float* sf     = (const float*)d_in[3];   // skip_feat (B,N,64)
    const int*   idxs   = (const int*)  d_in[4];   // upsampling_idxs (B,N,16)
    const float* W1     = (const float*)d_in[5];
    const float* b1     = (const float*)d_in[6];
    const float* g1     = (const float*)d_in[7];
    const float* be1    = (const float*)d_in[8];
    const float* W2     = (const float*)d_in[9];
    const float* b2     = (const float*)d_in[10];
    const float* g2     = (const float*)d_in[11];
    const float* be2    = (const float*)d_in[12];
    float* out = (float*)d_out;
    float* ws  = (float*)d_ws;

    (void)hipMemsetAsync(ws, 0, 1024, stream);  // zero the 256 stat floats
    k_proj<<<PROJ_BLOCKS, 256, 0, stream>>>(cf, idxs, scoord, sf,
                                            W1, b1, W2, b2, out, ws);
    k_fin<<<FIN_BLOCKS, 256, 0, stream>>>(out, ws, g1, be1, g2, be2);
}